// Round 10
// baseline (685.334 us; speedup 1.0000x reference)
//
#include <hip/hip_runtime.h>
#include <math.h>

// HE color normalization: NMF (100 mult-update iters) + 0.99-quantile + recompose.
// Single persistent kernel; V, Wc, Hd, Gram all register-resident.
// R9 = R6 (two-hop leader topology, epoch-tagged fire-and-forget u64 words,
// s_sleep spins, scalar stride-23 LDS scatter-tree) with the barrier diet:
//  - leader stage is barrier-free: leader wave0 lanes 0-21 batch-issue 16
//    member loads each (in flight), fold in fixed order, publish group word.
//  - final gather lands in sPrB (no post-publish barrier needed).
//  - per-wave register finalization of Hd/Gram (no final barrier, no loop-top
//    LDS reload). 3 __syncthreads per iteration (R6 had ~7).
// Summation nesting identical to R6 -> bitwise-identical results.

#define N_PIX (1024*1024)
#define NB    256            // blocks (1 per CU, co-resident)
#define BS    512            // threads/block (8 waves)
#define NWAVE (BS/64)
#define TT    (NB*BS)
#define PPT   (N_PIX/TT)     // 8 pixels per thread
#define NIT   100
#define EPSI  1e-8f
#define NBINS 2048
#define NGRP  16
#define TSTR  24             // u64 stride per tagged line (192B)
#define SSTR  23             // sAcc row stride (dwords) - coprime with 32 banks

// ---- workspace layout (byte offsets) ----
#define OFF_GH0_B 0
#define OFF_GH1_B 8192
#define OFF_T1_B  16384                          // [NB][2][TSTR] u64
#define OFF_T2_B  (16384 + NB*2*TSTR*8)          // [NGRP][2][TSTR] u64
#define WS_BYTES  (OFF_T2_B + NGRP*2*TSTR*8)

typedef unsigned long long u64;

__device__ __forceinline__ u64 ld_tag(const u64* p) {
    return __hip_atomic_load(p, __ATOMIC_RELAXED, __HIP_MEMORY_SCOPE_AGENT);
}
__device__ __forceinline__ void st_tag(u64* p, u64 v) {
    __hip_atomic_store(p, v, __ATOMIC_RELAXED, __HIP_MEMORY_SCOPE_AGENT);
}
__device__ __forceinline__ unsigned ld_rlx_u(const unsigned* p) {
    return __hip_atomic_load(p, __ATOMIC_RELAXED, __HIP_MEMORY_SCOPE_AGENT);
}
__device__ __forceinline__ u64 pack_tag(unsigned ep, float x) {
    return ((u64)ep << 32) | (u64)__float_as_uint(x);
}
__device__ __forceinline__ float spin_val(const u64* p, unsigned ep) {
    const u64 thr = ((u64)ep) << 32;
    u64 v = ld_tag(p);
    while (v < thr) { __builtin_amdgcn_s_sleep(1); v = ld_tag(p); }
    return __uint_as_float((unsigned)v);
}
__device__ __forceinline__ void spin_only(const u64* p, unsigned ep) {
    const u64 thr = ((u64)ep) << 32;
    while (ld_tag(p) < thr) __builtin_amdgcn_s_sleep(1);
}

__global__ __launch_bounds__(BS)
void he_norm_kernel(const float* __restrict__ pic,      // (3,N)
                    const float* __restrict__ Wt,       // (3,4)
                    const float* __restrict__ HtRM,     // scalar
                    const float* __restrict__ W0,       // (N,4)
                    const float* __restrict__ H0,       // (3,4)
                    float* __restrict__ out,            // (3,N)
                    unsigned char* __restrict__ ws)
{
    const int tid  = threadIdx.x;
    const int blk  = blockIdx.x;
    const int g    = blk*BS + tid;
    const int wave = tid >> 6;
    const int lane = tid & 63;
    const int grp  = blk >> 4;
    const int isLeader = ((blk & 15) == 0);
    const int grpBase  = grp << 4;

    unsigned* gh0 = (unsigned*)(ws + OFF_GH0_B);
    unsigned* gh1 = (unsigned*)(ws + OFF_GH1_B);
    u64*      T1  = (u64*)(ws + OFF_T1_B);
    u64*      T2  = (u64*)(ws + OFF_T2_B);

    __shared__ float sAcc[BS*SSTR];      // scatter buffer / tail scratch
    __shared__ float sPrA[16][22];       // block tree partials
    __shared__ float sPrB[16][22];       // final gather buffer
    __shared__ float sWv[NWAVE*24];      // per-wave finalize scratch
    __shared__ float sWt[12], sScal[2];
    __shared__ float sRed[NWAVE][2];
    __shared__ unsigned sHist[NBINS];
    __shared__ unsigned sSeg[256];
    __shared__ int      sBstar;
    __shared__ unsigned sCumB;

    // ---- setup: Wt to LDS; Hd, Gram into registers (identical per thread) ----
    if (tid < 12) sWt[tid] = Wt[tid];
    float hd[12], gg[16];
    #pragma unroll
    for (int j = 0; j < 12; j++) hd[j] = H0[j];
    #pragma unroll
    for (int j = 0; j < 16; j++) {
        int s_ = j >> 2, r_ = j & 3;
        gg[j] = hd[s_]*hd[r_] + hd[4+s_]*hd[4+r_] + hd[8+s_]*hd[8+r_];
    }

    // ---- persistent registers: V (optical density) and Wc ----
    float v0[PPT], v1[PPT], v2[PPT];
    float w[PPT][4];
    #pragma unroll
    for (int k = 0; k < PPT; k++) {
        int i = g + k*TT;
        float4 wv = ((const float4*)W0)[i];
        w[k][0]=wv.x; w[k][1]=wv.y; w[k][2]=wv.z; w[k][3]=wv.w;
        v0[k] = -logf(fminf(fmaxf(pic[i],           0.01f), 0.99f));
        v1[k] = -logf(fminf(fmaxf(pic[N_PIX  + i],  0.01f), 0.99f));
        v2[k] = -logf(fminf(fmaxf(pic[2*N_PIX + i], 0.01f), 0.99f));
    }
    __syncthreads();   // sWt ready

    // ---- NMF multiplicative updates ----
    for (int t = 0; t < NIT; ++t) {
        float acc[22];
        #pragma unroll
        for (int j = 0; j < 22; j++) acc[j] = 0.f;

        #pragma unroll
        for (int k = 0; k < PPT; k++) {
            float wn[4];
            #pragma unroll
            for (int r = 0; r < 4; r++) {
                float num = v0[k]*hd[r] + v1[k]*hd[4+r] + v2[k]*hd[8+r];
                float den = w[k][0]*gg[r] + w[k][1]*gg[4+r]
                          + w[k][2]*gg[8+r] + w[k][3]*gg[12+r] + EPSI;
                float rc = __builtin_amdgcn_rcpf(den);
                rc = rc * (2.0f - den*rc);          // 1 NR step: ~exact
                wn[r] = w[k][r] * num * rc;
            }
            #pragma unroll
            for (int r = 0; r < 4; r++) {
                acc[r]    += v0[k]*wn[r];
                acc[4+r]  += v1[k]*wn[r];
                acc[8+r]  += v2[k]*wn[r];
            }
            acc[12]+=wn[0]*wn[0]; acc[13]+=wn[0]*wn[1]; acc[14]+=wn[0]*wn[2]; acc[15]+=wn[0]*wn[3];
            acc[16]+=wn[1]*wn[1]; acc[17]+=wn[1]*wn[2]; acc[18]+=wn[1]*wn[3];
            acc[19]+=wn[2]*wn[2]; acc[20]+=wn[2]*wn[3]; acc[21]+=wn[3]*wn[3];
            w[k][0]=wn[0]; w[k][1]=wn[1]; w[k][2]=wn[2]; w[k][3]=wn[3];
        }

        if (t == NIT-1) break;   // last Hd update is dead code (output uses Wc only)
        const unsigned ep  = (unsigned)(t + 1);
        const int      par = (int)(ep & 1u);

        // ---- block reduce: scalar LDS scatter (stride 23) + tree ----
        #pragma unroll
        for (int j = 0; j < 22; j++) sAcc[tid*SSTR + j] = acc[j];
        __syncthreads();                                        // B1
        if (tid < 352) {
            int seg = tid / 22, j = tid - seg*22;
            const float* row = &sAcc[(seg*32)*SSTR + j];
            float p0=0.f, p1=0.f, p2=0.f, p3=0.f;
            #pragma unroll
            for (int b = 0; b < 32; b += 4) {
                p0 += row[(b+0)*SSTR]; p1 += row[(b+1)*SSTR];
                p2 += row[(b+2)*SSTR]; p3 += row[(b+3)*SSTR];
            }
            sPrA[seg][j] = (p0+p1)+(p2+p3);
        }
        __syncthreads();                                        // B2
        if (tid < 22) {                      // block partial -> tagged publish
            float bp = 0.f;
            #pragma unroll
            for (int sg = 0; sg < 16; sg++) bp += sPrA[sg][tid];
            st_tag(&T1[(blk*2 + par)*TSTR + tid], pack_tag(ep, bp));
        }

        // ---- leader stage: wave0 lanes 0-21, barrier-free batch gather ----
        if (isLeader && wave == 0 && lane < 22) {
            const u64 thr = ((u64)ep) << 32;
            u64 v[16];
            for (;;) {
                bool ok = true;
                #pragma unroll
                for (int m = 0; m < 16; m++)
                    v[m] = ld_tag(&T1[((grpBase + m)*2 + par)*TSTR + lane]);
                #pragma unroll
                for (int m = 0; m < 16; m++) ok &= (v[m] >= thr);
                if (ok) break;
                __builtin_amdgcn_s_sleep(1);
            }
            float gp = 0.f;
            #pragma unroll
            for (int m = 0; m < 16; m++) gp += __uint_as_float((unsigned)v[m]);
            st_tag(&T2[(grp*2 + par)*TSTR + lane], pack_tag(ep, gp));
        }

        // ---- all blocks: fused detect+gather of 16 group words -> sPrB ----
        if (tid < 352) {
            int g2 = tid / 22, j = tid - g2*22;
            sPrB[g2][j] = spin_val(&T2[(g2*2 + par)*TSTR + j], ep);
        }
        __syncthreads();                                        // B3

        // ---- per-wave finalization: Hd + Gram in registers ----
        {
            if (lane < 22) {
                float s = 0.f;
                #pragma unroll
                for (int m = 0; m < 16; m++) s += sPrB[m][lane];
                sWv[wave*24 + lane] = s;
            }
            float ss[22];
            #pragma unroll
            for (int j = 0; j < 22; j++) ss[j] = sWv[wave*24 + j];
            float nhd[12];
            const int base[4] = {12, 16, 19, 21};
            #pragma unroll
            for (int c = 0; c < 3; c++)
                #pragma unroll
                for (int r = 0; r < 4; r++) {
                    float den = EPSI;
                    #pragma unroll
                    for (int s2 = 0; s2 < 4; s2++) {
                        int lo = (s2 < r) ? s2 : r, hi = (s2 < r) ? r : s2;
                        den += hd[c*4 + s2] * ss[base[lo] + (hi - lo)];
                    }
                    nhd[c*4+r] = hd[c*4+r] * ss[c*4+r] / den;
                }
            #pragma unroll
            for (int j = 0; j < 12; j++) hd[j] = nhd[j];
            #pragma unroll
            for (int j = 0; j < 16; j++) {
                int s_ = j >> 2, r_ = j & 3;
                gg[j] = hd[s_]*hd[r_] + hd[4+s_]*hd[4+r_] + hd[8+s_]*hd[8+r_];
            }
        }
    }

    // ================= tail: quantile + recompose =================
    // ---- ep=100 (par 0, word 0): global max of Wc ----
    {
        float m = 0.f;
        #pragma unroll
        for (int k = 0; k < PPT; k++)
            #pragma unroll
            for (int r = 0; r < 4; r++) m = fmaxf(m, w[k][r]);
        #pragma unroll
        for (int off = 32; off > 0; off >>= 1) m = fmaxf(m, __shfl_down(m, off, 64));
        if (lane == 0) sRed[wave][0] = m;
        __syncthreads();
        if (tid == 0) {
            float mm = 0.f;
            for (int wv2 = 0; wv2 < NWAVE; wv2++) mm = fmaxf(mm, sRed[wv2][0]);
            st_tag(&T1[(blk*2 + 0)*TSTR + 0], pack_tag(100u, mm));
        }
        if (tid < NB) sAcc[tid] = spin_val(&T1[(tid*2 + 0)*TSTR + 0], 100u);
        __syncthreads();
        if (tid < NB) {
            float mv = sAcc[tid];
            #pragma unroll
            for (int off = 32; off > 0; off >>= 1) mv = fmaxf(mv, __shfl_down(mv, off, 64));
            if (lane == 0) sRed[wave][1] = mv;
        }
        __syncthreads();
        if (tid == 0) {
            float mm = 0.f;
            for (int wv2 = 0; wv2 < 4; wv2++) mm = fmaxf(mm, sRed[wv2][1]);
            sScal[0] = mm * 1.0000002f;
        }
        __syncthreads();
    }
    const float gmax   = sScal[0];
    const float scale0 = (float)NBINS / gmax;

    // ---- ep=101 (par 1, word 0): histogram level 0 ----
    for (int i = tid; i < NBINS; i += BS) sHist[i] = 0u;
    __syncthreads();
    #pragma unroll
    for (int k = 0; k < PPT; k++)
        #pragma unroll
        for (int r = 0; r < 4; r++) {
            int b = (int)(w[k][r] * scale0);
            b = min(b, NBINS - 1);
            atomicAdd(&sHist[b], 1u);
        }
    __syncthreads();
    for (int i = tid; i < NBINS; i += BS) if (sHist[i]) atomicAdd(&gh0[i], sHist[i]);
    __builtin_amdgcn_s_waitcnt(0);      // every wave: its hist atomics acked
    __syncthreads();
    if (tid == 0) st_tag(&T1[(blk*2 + 1)*TSTR + 0], pack_tag(101u, 0.f));
    if (tid < NB) spin_only(&T1[(tid*2 + 1)*TSTR + 0], 101u);
    __syncthreads();

    // ---- scan level 0 (redundant in every block, exact integer counts) ----
    const double kfd = 0.99 * (double)(4*N_PIX - 1);   // fractional rank
    if (tid < 256) {
        unsigned s2 = 0;
        for (int i = 0; i < 8; i++) s2 += ld_rlx_u(&gh0[tid*8 + i]);
        sSeg[tid] = s2;
    }
    __syncthreads();
    if (tid == 0) {
        unsigned cum = 0; int seg = 0;
        for (int i2 = 0; i2 < 256; i2++) {
            if ((double)(cum + sSeg[i2]) > kfd) { seg = i2; break; }
            cum += sSeg[i2];
        }
        unsigned c2 = cum; int b = seg*8;
        for (int i2 = 0; i2 < 8; i2++) {
            unsigned h = ld_rlx_u(&gh0[seg*8 + i2]);
            if ((double)(c2 + h) > kfd) { b = seg*8 + i2; break; }
            c2 += h;
        }
        sBstar = b; sCumB = c2;
    }
    __syncthreads();
    const int   bstar  = sBstar;
    const float lo1    = (float)bstar / scale0;
    const float scale1 = scale0 * (float)NBINS;

    // ---- ep=102 (par 0, word 0): histogram level 1 ----
    for (int i = tid; i < NBINS; i += BS) sHist[i] = 0u;
    __syncthreads();
    #pragma unroll
    for (int k = 0; k < PPT; k++)
        #pragma unroll
        for (int r = 0; r < 4; r++) {
            int b0 = min((int)(w[k][r] * scale0), NBINS - 1);
            if (b0 == bstar) {
                int b1 = (int)((w[k][r] - lo1) * scale1);
                b1 = max(0, min(b1, NBINS - 1));
                atomicAdd(&sHist[b1], 1u);
            }
        }
    __syncthreads();
    for (int i = tid; i < NBINS; i += BS) if (sHist[i]) atomicAdd(&gh1[i], sHist[i]);
    __builtin_amdgcn_s_waitcnt(0);
    __syncthreads();
    if (tid == 0) st_tag(&T1[(blk*2 + 0)*TSTR + 0], pack_tag(102u, 0.f));
    if (tid < NB) spin_only(&T1[(tid*2 + 0)*TSTR + 0], 102u);
    __syncthreads();

    // ---- scan level 1 -> quantile -> scale factor (redundant) ----
    if (tid < 256) {
        unsigned s2 = 0;
        for (int i = 0; i < 8; i++) s2 += ld_rlx_u(&gh1[tid*8 + i]);
        sSeg[tid] = s2;
    }
    __syncthreads();
    if (tid == 0) {
        double jf = kfd - (double)sCumB;
        unsigned cum = 0; int seg = 0;
        for (int i2 = 0; i2 < 256; i2++) {
            if ((double)(cum + sSeg[i2]) > jf) { seg = i2; break; }
            cum += sSeg[i2];
        }
        unsigned c3 = cum; int bb = seg*8; unsigned hh = 1;
        for (int i2 = 0; i2 < 8; i2++) {
            unsigned h = ld_rlx_u(&gh1[seg*8 + i2]);
            if ((double)(c3 + h) > jf) { bb = seg*8 + i2; hh = h; break; }
            c3 += h;
        }
        double frac = (jf - (double)c3 + 0.5) / (double)hh;
        frac = fmin(fmax(frac, 0.0), 1.0);
        double q = (double)lo1 + ((double)bb + frac) / (double)scale1;
        sScal[1] = (float)((double)HtRM[0] / q);
    }
    __syncthreads();
    const float sc = sScal[1];

    // ---- recompose: out = clip(exp(-(Wt @ (Wc^T * sc))), 0, 1) ----
    #pragma unroll
    for (int k = 0; k < PPT; k++) {
        int i = g + k*TT;
        #pragma unroll
        for (int c = 0; c < 3; c++) {
            float d = sWt[c*4+0]*w[k][0] + sWt[c*4+1]*w[k][1]
                    + sWt[c*4+2]*w[k][2] + sWt[c*4+3]*w[k][3];
            float e = expf(-d * sc);
            out[c*N_PIX + i] = fminf(fmaxf(e, 0.f), 1.f);
        }
    }
}

extern "C" void kernel_launch(void* const* d_in, const int* in_sizes, int n_in,
                              void* d_out, int out_size, void* d_ws, size_t ws_size,
                              hipStream_t stream) {
    const float* pic  = (const float*)d_in[0];
    const float* Wt   = (const float*)d_in[1];
    const float* HtRM = (const float*)d_in[2];
    const float* W0   = (const float*)d_in[3];
    const float* H0   = (const float*)d_in[4];
    float* out = (float*)d_out;

    // zero histograms + tagged-word regions (tags start at epoch 0)
    hipMemsetAsync(d_ws, 0, WS_BYTES, stream);
    he_norm_kernel<<<dim3(NB), dim3(BS), 0, stream>>>(
        pic, Wt, HtRM, W0, H0, out, (unsigned char*)d_ws);
}

// Round 11
// 557.098 us; speedup vs baseline: 1.2302x; 1.2302x over previous
//
#include <hip/hip_runtime.h>
#include <math.h>

// HE color normalization: NMF (100 mult-update iters) + 0.99-quantile + recompose.
// Single persistent kernel; V, Wc register-resident; Hd/Gram in LDS (wave0-owned).
// R10 = R6 (best measured: two-hop leader topology, epoch-tagged fire-and-forget
// u64 words, s_sleep spins, wave0-only Hd update) + barrier diet WITHOUT adding
// VALU (R8/R9 lesson: redundant per-wave finalize cost 1.1us/iter):
//  - wave-local block reduce: each wave scatters to its own stride-23 region and
//    reads back in-wave (same-wave LDS ordering, no barrier) -> 8 wave partials;
//    one barrier; wave0 folds+publishes. (was scatter/B1/tree/B2/fold)
//  - final T2 gather lands in sPrB (drops post-publish barrier)
//  - wave0-fused finalize: sum->sS->Hd->Gram in-wave, single trailing barrier.
// 3 __syncthreads/iter for non-leaders (R6 had 6).

#define N_PIX (1024*1024)
#define NB    256            // blocks (1 per CU, co-resident)
#define BS    512            // threads/block (8 waves)
#define NWAVE (BS/64)
#define TT    (NB*BS)
#define PPT   (N_PIX/TT)     // 8 pixels per thread
#define NIT   100
#define EPSI  1e-8f
#define NBINS 2048
#define NGRP  16
#define TSTR  24             // u64 stride per tagged line (192B)
#define SSTR  23             // sAcc row stride (dwords) - coprime with 32 banks

// ---- workspace layout (byte offsets) ----
#define OFF_GH0_B 0
#define OFF_GH1_B 8192
#define OFF_T1_B  16384                          // [NB][2][TSTR] u64
#define OFF_T2_B  (16384 + NB*2*TSTR*8)          // [NGRP][2][TSTR] u64
#define WS_BYTES  (OFF_T2_B + NGRP*2*TSTR*8)

typedef unsigned long long u64;

__device__ __forceinline__ u64 ld_tag(const u64* p) {
    return __hip_atomic_load(p, __ATOMIC_RELAXED, __HIP_MEMORY_SCOPE_AGENT);
}
__device__ __forceinline__ void st_tag(u64* p, u64 v) {
    __hip_atomic_store(p, v, __ATOMIC_RELAXED, __HIP_MEMORY_SCOPE_AGENT);
}
__device__ __forceinline__ unsigned ld_rlx_u(const unsigned* p) {
    return __hip_atomic_load(p, __ATOMIC_RELAXED, __HIP_MEMORY_SCOPE_AGENT);
}
__device__ __forceinline__ u64 pack_tag(unsigned ep, float x) {
    return ((u64)ep << 32) | (u64)__float_as_uint(x);
}
__device__ __forceinline__ float spin_val(const u64* p, unsigned ep) {
    const u64 thr = ((u64)ep) << 32;
    u64 v = ld_tag(p);
    while (v < thr) { __builtin_amdgcn_s_sleep(1); v = ld_tag(p); }
    return __uint_as_float((unsigned)v);
}
__device__ __forceinline__ void spin_only(const u64* p, unsigned ep) {
    const u64 thr = ((u64)ep) << 32;
    while (ld_tag(p) < thr) __builtin_amdgcn_s_sleep(1);
}

__global__ __launch_bounds__(BS)
void he_norm_kernel(const float* __restrict__ pic,      // (3,N)
                    const float* __restrict__ Wt,       // (3,4)
                    const float* __restrict__ HtRM,     // scalar
                    const float* __restrict__ W0,       // (N,4)
                    const float* __restrict__ H0,       // (3,4)
                    float* __restrict__ out,            // (3,N)
                    unsigned char* __restrict__ ws)
{
    const int tid  = threadIdx.x;
    const int blk  = blockIdx.x;
    const int g    = blk*BS + tid;
    const int wave = tid >> 6;
    const int lane = tid & 63;
    const int grp  = blk >> 4;
    const int isLeader = ((blk & 15) == 0);
    const int grpBase  = grp << 4;

    unsigned* gh0 = (unsigned*)(ws + OFF_GH0_B);
    unsigned* gh1 = (unsigned*)(ws + OFF_GH1_B);
    u64*      T1  = (u64*)(ws + OFF_T1_B);
    u64*      T2  = (u64*)(ws + OFF_T2_B);

    __shared__ float sAcc[BS*SSTR];      // scatter buffer / tail scratch
    __shared__ float sPrA[16][22];       // leader gather buffer
    __shared__ float sPrB[16][22];       // final gather buffer
    __shared__ float sRed[NWAVE][24];    // wave partials
    __shared__ float sS[22], sHd[12], sG[16], sWt[12], sScal[2];
    __shared__ unsigned sHist[NBINS];
    __shared__ unsigned sSeg[256];
    __shared__ int      sBstar;
    __shared__ unsigned sCumB;

    // ---- setup ----
    if (tid < 12) { sHd[tid] = H0[tid]; sWt[tid] = Wt[tid]; }
    __syncthreads();
    if (tid < 16) {
        int s_ = tid >> 2, r_ = tid & 3;
        sG[tid] = sHd[s_]*sHd[r_] + sHd[4+s_]*sHd[4+r_] + sHd[8+s_]*sHd[8+r_];
    }

    // ---- persistent registers: V (optical density) and Wc ----
    float v0[PPT], v1[PPT], v2[PPT];
    float w[PPT][4];
    #pragma unroll
    for (int k = 0; k < PPT; k++) {
        int i = g + k*TT;
        float4 wv = ((const float4*)W0)[i];
        w[k][0]=wv.x; w[k][1]=wv.y; w[k][2]=wv.z; w[k][3]=wv.w;
        v0[k] = -logf(fminf(fmaxf(pic[i],           0.01f), 0.99f));
        v1[k] = -logf(fminf(fmaxf(pic[N_PIX  + i],  0.01f), 0.99f));
        v2[k] = -logf(fminf(fmaxf(pic[2*N_PIX + i], 0.01f), 0.99f));
    }
    __syncthreads();   // sHd/sG ready

    // ---- NMF multiplicative updates ----
    for (int t = 0; t < NIT; ++t) {
        float hd[12], gg[16];
        #pragma unroll
        for (int j = 0; j < 12; j++) hd[j] = sHd[j];
        #pragma unroll
        for (int j = 0; j < 16; j++) gg[j] = sG[j];

        float acc[22];
        #pragma unroll
        for (int j = 0; j < 22; j++) acc[j] = 0.f;

        #pragma unroll
        for (int k = 0; k < PPT; k++) {
            float wn[4];
            #pragma unroll
            for (int r = 0; r < 4; r++) {
                float num = v0[k]*hd[r] + v1[k]*hd[4+r] + v2[k]*hd[8+r];
                float den = w[k][0]*gg[r] + w[k][1]*gg[4+r]
                          + w[k][2]*gg[8+r] + w[k][3]*gg[12+r] + EPSI;
                float rc = __builtin_amdgcn_rcpf(den);
                rc = rc * (2.0f - den*rc);          // 1 NR step: ~exact
                wn[r] = w[k][r] * num * rc;
            }
            #pragma unroll
            for (int r = 0; r < 4; r++) {
                acc[r]    += v0[k]*wn[r];
                acc[4+r]  += v1[k]*wn[r];
                acc[8+r]  += v2[k]*wn[r];
            }
            acc[12]+=wn[0]*wn[0]; acc[13]+=wn[0]*wn[1]; acc[14]+=wn[0]*wn[2]; acc[15]+=wn[0]*wn[3];
            acc[16]+=wn[1]*wn[1]; acc[17]+=wn[1]*wn[2]; acc[18]+=wn[1]*wn[3];
            acc[19]+=wn[2]*wn[2]; acc[20]+=wn[2]*wn[3]; acc[21]+=wn[3]*wn[3];
            w[k][0]=wn[0]; w[k][1]=wn[1]; w[k][2]=wn[2]; w[k][3]=wn[3];
        }

        if (t == NIT-1) break;   // last Hd update is dead code (output uses Wc only)
        const unsigned ep  = (unsigned)(t + 1);
        const int      par = (int)(ep & 1u);

        // ---- wave-local block reduce (no barrier: same-wave LDS ordering) ----
        #pragma unroll
        for (int j = 0; j < 22; j++) sAcc[tid*SSTR + j] = acc[j];
        if (lane < 22) {
            const float* row = &sAcc[(wave*64)*SSTR + lane];
            float p0=0.f, p1=0.f, p2=0.f, p3=0.f;
            #pragma unroll
            for (int b = 0; b < 64; b += 4) {
                p0 += row[(b+0)*SSTR]; p1 += row[(b+1)*SSTR];
                p2 += row[(b+2)*SSTR]; p3 += row[(b+3)*SSTR];
            }
            sRed[wave][lane] = (p0+p1)+(p2+p3);
        }
        __syncthreads();                                        // B_A

        // ---- wave0 folds 8 wave partials, publishes tagged block line ----
        if (wave == 0 && lane < 22) {
            float bp = 0.f;
            #pragma unroll
            for (int wv = 0; wv < NWAVE; wv++) bp += sRed[wv][lane];
            st_tag(&T1[(blk*2 + par)*TSTR + lane], pack_tag(ep, bp));
        }

        // ---- leader stage: gather 16 member lines, fold, publish group word ----
        if (isLeader) {
            if (tid < 352) {
                int m = tid / 22, j = tid - m*22;
                sPrA[m][j] = spin_val(&T1[((grpBase + m)*2 + par)*TSTR + j], ep);
            }
            __syncthreads();                                    // B4L (leaders only)
            if (tid < 22) {
                float gp = 0.f;
                #pragma unroll
                for (int m = 0; m < 16; m++) gp += sPrA[m][tid];
                st_tag(&T2[(grp*2 + par)*TSTR + tid], pack_tag(ep, gp));
            }
        }

        // ---- all blocks: fused detect+gather of 16 group words -> sPrB ----
        if (tid < 352) {
            int g2 = tid / 22, j = tid - g2*22;
            sPrB[g2][j] = spin_val(&T2[(g2*2 + par)*TSTR + j], ep);
        }
        __syncthreads();                                        // B6

        // ---- wave0-fused finalization: sum -> sS -> Hd -> Gram (in-wave) ----
        if (wave == 0) {
            if (lane < 22) {
                float s = 0.f;
                #pragma unroll
                for (int g2 = 0; g2 < 16; g2++) s += sPrB[g2][lane];
                sS[lane] = s;
            }
            if (lane < 12) {
                int c = lane >> 2, r = lane & 3;
                const int base[4] = {12, 16, 19, 21};
                float den = EPSI;
                #pragma unroll
                for (int s2 = 0; s2 < 4; s2++) {
                    int lo = (s2 < r) ? s2 : r, hi = (s2 < r) ? r : s2;
                    den += sHd[c*4 + s2] * sS[base[lo] + (hi - lo)];
                }
                float nhd = sHd[lane] * sS[lane] / den;
                sHd[lane] = nhd;            // in-wave: reads above precede write
            }
            if (lane < 16) {                // reads new sHd, in-wave ordered
                int s_ = lane >> 2, r_ = lane & 3;
                sG[lane] = sHd[s_]*sHd[r_] + sHd[4+s_]*sHd[4+r_] + sHd[8+s_]*sHd[8+r_];
            }
        }
        __syncthreads();                                        // B7
    }

    // ================= tail: quantile + recompose =================
    // ---- ep=100 (par 0, word 0): global max of Wc ----
    {
        float m = 0.f;
        #pragma unroll
        for (int k = 0; k < PPT; k++)
            #pragma unroll
            for (int r = 0; r < 4; r++) m = fmaxf(m, w[k][r]);
        #pragma unroll
        for (int off = 32; off > 0; off >>= 1) m = fmaxf(m, __shfl_down(m, off, 64));
        if (lane == 0) sRed[wave][0] = m;
        __syncthreads();
        if (tid == 0) {
            float mm = 0.f;
            for (int wv2 = 0; wv2 < NWAVE; wv2++) mm = fmaxf(mm, sRed[wv2][0]);
            st_tag(&T1[(blk*2 + 0)*TSTR + 0], pack_tag(100u, mm));
        }
        if (tid < NB) sAcc[tid] = spin_val(&T1[(tid*2 + 0)*TSTR + 0], 100u);
        __syncthreads();
        if (tid < NB) {
            float mv = sAcc[tid];
            #pragma unroll
            for (int off = 32; off > 0; off >>= 1) mv = fmaxf(mv, __shfl_down(mv, off, 64));
            if (lane == 0) sRed[wave][1] = mv;
        }
        __syncthreads();
        if (tid == 0) {
            float mm = 0.f;
            for (int wv2 = 0; wv2 < 4; wv2++) mm = fmaxf(mm, sRed[wv2][1]);
            sScal[0] = mm * 1.0000002f;
        }
        __syncthreads();
    }
    const float gmax   = sScal[0];
    const float scale0 = (float)NBINS / gmax;

    // ---- ep=101 (par 1, word 0): histogram level 0 ----
    for (int i = tid; i < NBINS; i += BS) sHist[i] = 0u;
    __syncthreads();
    #pragma unroll
    for (int k = 0; k < PPT; k++)
        #pragma unroll
        for (int r = 0; r < 4; r++) {
            int b = (int)(w[k][r] * scale0);
            b = min(b, NBINS - 1);
            atomicAdd(&sHist[b], 1u);
        }
    __syncthreads();
    for (int i = tid; i < NBINS; i += BS) if (sHist[i]) atomicAdd(&gh0[i], sHist[i]);
    __builtin_amdgcn_s_waitcnt(0);      // every wave: its hist atomics acked
    __syncthreads();
    if (tid == 0) st_tag(&T1[(blk*2 + 1)*TSTR + 0], pack_tag(101u, 0.f));
    if (tid < NB) spin_only(&T1[(tid*2 + 1)*TSTR + 0], 101u);
    __syncthreads();

    // ---- scan level 0 (redundant in every block, exact integer counts) ----
    const double kfd = 0.99 * (double)(4*N_PIX - 1);   // fractional rank
    if (tid < 256) {
        unsigned s2 = 0;
        for (int i = 0; i < 8; i++) s2 += ld_rlx_u(&gh0[tid*8 + i]);
        sSeg[tid] = s2;
    }
    __syncthreads();
    if (tid == 0) {
        unsigned cum = 0; int seg = 0;
        for (int i2 = 0; i2 < 256; i2++) {
            if ((double)(cum + sSeg[i2]) > kfd) { seg = i2; break; }
            cum += sSeg[i2];
        }
        unsigned c2 = cum; int b = seg*8;
        for (int i2 = 0; i2 < 8; i2++) {
            unsigned h = ld_rlx_u(&gh0[seg*8 + i2]);
            if ((double)(c2 + h) > kfd) { b = seg*8 + i2; break; }
            c2 += h;
        }
        sBstar = b; sCumB = c2;
    }
    __syncthreads();
    const int   bstar  = sBstar;
    const float lo1    = (float)bstar / scale0;
    const float scale1 = scale0 * (float)NBINS;

    // ---- ep=102 (par 0, word 0): histogram level 1 ----
    for (int i = tid; i < NBINS; i += BS) sHist[i] = 0u;
    __syncthreads();
    #pragma unroll
    for (int k = 0; k < PPT; k++)
        #pragma unroll
        for (int r = 0; r < 4; r++) {
            int b0 = min((int)(w[k][r] * scale0), NBINS - 1);
            if (b0 == bstar) {
                int b1 = (int)((w[k][r] - lo1) * scale1);
                b1 = max(0, min(b1, NBINS - 1));
                atomicAdd(&sHist[b1], 1u);
            }
        }
    __syncthreads();
    for (int i = tid; i < NBINS; i += BS) if (sHist[i]) atomicAdd(&gh1[i], sHist[i]);
    __builtin_amdgcn_s_waitcnt(0);
    __syncthreads();
    if (tid == 0) st_tag(&T1[(blk*2 + 0)*TSTR + 0], pack_tag(102u, 0.f));
    if (tid < NB) spin_only(&T1[(tid*2 + 0)*TSTR + 0], 102u);
    __syncthreads();

    // ---- scan level 1 -> quantile -> scale factor (redundant) ----
    if (tid < 256) {
        unsigned s2 = 0;
        for (int i = 0; i < 8; i++) s2 += ld_rlx_u(&gh1[tid*8 + i]);
        sSeg[tid] = s2;
    }
    __syncthreads();
    if (tid == 0) {
        double jf = kfd - (double)sCumB;
        unsigned cum = 0; int seg = 0;
        for (int i2 = 0; i2 < 256; i2++) {
            if ((double)(cum + sSeg[i2]) > jf) { seg = i2; break; }
            cum += sSeg[i2];
        }
        unsigned c3 = cum; int bb = seg*8; unsigned hh = 1;
        for (int i2 = 0; i2 < 8; i2++) {
            unsigned h = ld_rlx_u(&gh1[seg*8 + i2]);
            if ((double)(c3 + h) > jf) { bb = seg*8 + i2; hh = h; break; }
            c3 += h;
        }
        double frac = (jf - (double)c3 + 0.5) / (double)hh;
        frac = fmin(fmax(frac, 0.0), 1.0);
        double q = (double)lo1 + ((double)bb + frac) / (double)scale1;
        sScal[1] = (float)((double)HtRM[0] / q);
    }
    __syncthreads();
    const float sc = sScal[1];

    // ---- recompose: out = clip(exp(-(Wt @ (Wc^T * sc))), 0, 1) ----
    #pragma unroll
    for (int k = 0; k < PPT; k++) {
        int i = g + k*TT;
        #pragma unroll
        for (int c = 0; c < 3; c++) {
            float d = sWt[c*4+0]*w[k][0] + sWt[c*4+1]*w[k][1]
                    + sWt[c*4+2]*w[k][2] + sWt[c*4+3]*w[k][3];
            float e = expf(-d * sc);
            out[c*N_PIX + i] = fminf(fmaxf(e, 0.f), 1.f);
        }
    }
}

extern "C" void kernel_launch(void* const* d_in, const int* in_sizes, int n_in,
                              void* d_out, int out_size, void* d_ws, size_t ws_size,
                              hipStream_t stream) {
    const float* pic  = (const float*)d_in[0];
    const float* Wt   = (const float*)d_in[1];
    const float* HtRM = (const float*)d_in[2];
    const float* W0   = (const float*)d_in[3];
    const float* H0   = (const float*)d_in[4];
    float* out = (float*)d_out;

    // zero histograms + tagged-word regions (tags start at epoch 0)
    hipMemsetAsync(d_ws, 0, WS_BYTES, stream);
    he_norm_kernel<<<dim3(NB), dim3(BS), 0, stream>>>(
        pic, Wt, HtRM, W0, H0, out, (unsigned char*)d_ws);
}